// Round 1
// baseline (332.602 us; speedup 1.0000x reference)
//
#include <hip/hip_runtime.h>
#include <cstdint>
#include <cstddef>

#define N_NODES 50000
#define N_EDGES 800000
#define DIM_IN  128
#define DIM_OUT 64

// ---------------------------------------------------------------------------
// Kernel 1: zero the output accumulator, init deg[n] = 1 (self-loop).
// ---------------------------------------------------------------------------
__global__ __launch_bounds__(256) void k_init(float* __restrict__ out,
                                              int* __restrict__ deg) {
    int i = blockIdx.x * 256 + threadIdx.x;
    if (i < N_NODES * DIM_OUT) out[i] = 0.0f;
    if (i < N_NODES) deg[i] = 1;
}

// ---------------------------------------------------------------------------
// Kernel 2: in-degree histogram over dst.
// ---------------------------------------------------------------------------
__global__ __launch_bounds__(256) void k_deg(const int* __restrict__ ei,
                                             int* __restrict__ deg) {
    int e = blockIdx.x * 256 + threadIdx.x;
    if (e < N_EDGES) {
        int dst = ei[N_EDGES + e];
        atomicAdd(&deg[dst], 1);
    }
}

// ---------------------------------------------------------------------------
// Kernel 3: dinv[n] = rsqrt(deg[n])   (deg >= 1 always, self-loop included)
// ---------------------------------------------------------------------------
__global__ __launch_bounds__(256) void k_dinv(const int* __restrict__ deg,
                                              float* __restrict__ dinv) {
    int i = blockIdx.x * 256 + threadIdx.x;
    if (i < N_NODES) dinv[i] = rsqrtf((float)deg[i]);
}

// ---------------------------------------------------------------------------
// Kernel 4: h_scaled[n,:] = (x[n,:] @ W) * dinv[n]
// Block = 256 threads = 4 waves; block handles 16 rows (4 rows per wave).
// W (128x64 = 32 KB) staged in LDS; 16 x-rows (8 KB) staged in LDS.
// Within a wave: col = lane (Wl read is 2-lanes/bank, free), row/k are
// wave-uniform (Xl reads broadcast). 50000/16 = 3125 blocks exactly.
// ---------------------------------------------------------------------------
__global__ __launch_bounds__(256) void k_gemm(const float* __restrict__ x,
                                              const float* __restrict__ W,
                                              const float* __restrict__ dinv,
                                              float* __restrict__ h) {
    __shared__ float Wl[DIM_IN * DIM_OUT];   // [k][col], 32 KB
    __shared__ float Xl[16 * DIM_IN];        // [row][k], 8 KB

    const int t = threadIdx.x;
    const int rowBase = blockIdx.x * 16;

    for (int i = t; i < DIM_IN * DIM_OUT; i += 256) Wl[i] = W[i];
    const float* xg = x + (size_t)rowBase * DIM_IN;
    for (int i = t; i < 16 * DIM_IN; i += 256) Xl[i] = xg[i];
    __syncthreads();

    const int lane = t & 63;
    const int wv   = t >> 6;        // wave-uniform 0..3
    const int r0   = wv * 4;

    float acc0 = 0.f, acc1 = 0.f, acc2 = 0.f, acc3 = 0.f;
#pragma unroll 8
    for (int k = 0; k < DIM_IN; ++k) {
        float w = Wl[k * DIM_OUT + lane];
        acc0 = fmaf(Xl[(r0 + 0) * DIM_IN + k], w, acc0);
        acc1 = fmaf(Xl[(r0 + 1) * DIM_IN + k], w, acc1);
        acc2 = fmaf(Xl[(r0 + 2) * DIM_IN + k], w, acc2);
        acc3 = fmaf(Xl[(r0 + 3) * DIM_IN + k], w, acc3);
    }

    const int row = rowBase + r0;
    h[(size_t)(row + 0) * DIM_OUT + lane] = acc0 * dinv[row + 0];
    h[(size_t)(row + 1) * DIM_OUT + lane] = acc1 * dinv[row + 1];
    h[(size_t)(row + 2) * DIM_OUT + lane] = acc2 * dinv[row + 2];
    h[(size_t)(row + 3) * DIM_OUT + lane] = acc3 * dinv[row + 3];
}

// ---------------------------------------------------------------------------
// Kernel 5: edge scatter. One 64-lane wave per edge, lane = channel.
// out[dst,:] += h_scaled[src,:] * dinv[dst]   (atomic f32 add)
// 800000 / 4 edges-per-block = 200000 blocks exactly.
// ---------------------------------------------------------------------------
__global__ __launch_bounds__(256) void k_scatter(const int* __restrict__ ei,
                                                 const float* __restrict__ h,
                                                 const float* __restrict__ dinv,
                                                 float* __restrict__ out) {
    const int e = blockIdx.x * 4 + (threadIdx.x >> 6);
    const int lane = threadIdx.x & 63;
    const int src = ei[e];
    const int dst = ei[N_EDGES + e];
    const float v = h[(size_t)src * DIM_OUT + lane] * dinv[dst];
    atomicAdd(&out[(size_t)dst * DIM_OUT + lane], v);
}

// ---------------------------------------------------------------------------
// Kernel 6: add self-loop message + bias, then log_softmax over 64 channels.
// One wave per node; 64-lane shuffle reductions for max and sum.
// ---------------------------------------------------------------------------
__global__ __launch_bounds__(256) void k_final(const float* __restrict__ h,
                                               const float* __restrict__ dinv,
                                               const float* __restrict__ b,
                                               float* __restrict__ out) {
    const int n = blockIdx.x * 4 + (threadIdx.x >> 6);
    if (n >= N_NODES) return;
    const int lane = threadIdx.x & 63;

    const float di = dinv[n];
    float v = out[(size_t)n * DIM_OUT + lane]
            + h[(size_t)n * DIM_OUT + lane] * di
            + b[lane];

    float m = v;
#pragma unroll
    for (int off = 32; off > 0; off >>= 1) m = fmaxf(m, __shfl_xor(m, off));
    float ex = __expf(v - m);
    float s = ex;
#pragma unroll
    for (int off = 32; off > 0; off >>= 1) s += __shfl_xor(s, off);

    out[(size_t)n * DIM_OUT + lane] = v - m - __logf(s);
}

// ---------------------------------------------------------------------------
extern "C" void kernel_launch(void* const* d_in, const int* in_sizes, int n_in,
                              void* d_out, int out_size, void* d_ws, size_t ws_size,
                              hipStream_t stream) {
    const float* x  = (const float*)d_in[0];
    const int*   ei = (const int*)d_in[1];     // [2, E]: row0 = src, row1 = dst
    const float* W  = (const float*)d_in[2];
    const float* b  = (const float*)d_in[3];
    float* out = (float*)d_out;

    // workspace layout: h_scaled (N*64 f32 = 12.8 MB) | dinv (N f32) | deg (N i32)
    char* ws = (char*)d_ws;
    float* h    = (float*)ws;
    float* dinv = (float*)(ws + (size_t)N_NODES * DIM_OUT * sizeof(float));
    int*   deg  = (int*)  (ws + (size_t)N_NODES * DIM_OUT * sizeof(float)
                              + (size_t)N_NODES * sizeof(float));

    k_init   <<<(N_NODES * DIM_OUT + 255) / 256, 256, 0, stream>>>(out, deg);
    k_deg    <<<(N_EDGES + 255) / 256,           256, 0, stream>>>(ei, deg);
    k_dinv   <<<(N_NODES + 255) / 256,           256, 0, stream>>>(deg, dinv);
    k_gemm   <<<N_NODES / 16,                    256, 0, stream>>>(x, W, dinv, h);
    k_scatter<<<N_EDGES / 4,                     256, 0, stream>>>(ei, h, dinv, out);
    k_final  <<<(N_NODES + 3) / 4,               256, 0, stream>>>(h, dinv, b, out);
}